// Round 7
// baseline (136.137 us; speedup 1.0000x reference)
//
#include <hip/hip_runtime.h>

// SelfAttention_33852932227207 — MI355X, round 7.
// e = x^T (Wq^T Wa Wk) x / sqrt(512);  out = softmax(e) @ (x (Wb Wv)^T).
// Round-7: GEMM schedule upgrade on the round-6-proven machinery.
//  * all 3 big GEMMs: issue-early double-buffered LDS staging, ONE
//    vmcnt(0)+barrier per K-step (loads fly under the MFMA cluster), setprio.
//  * k_score / k_proj(KP): operand-swapped so epilogues store ushort4.
//  * k_proj: XCD-pinned 1D grid (rb-chunks per XCD -> L2-resident tiles).
//  * merged prep kernel (split_x + weight prep + l zero); no memset launch.

typedef __attribute__((ext_vector_type(8))) short b16x8;
typedef __attribute__((ext_vector_type(4))) float f4;
typedef unsigned short u16;

#define DEVINL __device__ __forceinline__

DEVINL u16 f2bf(float f) {               // fp32 -> bf16 RNE
  unsigned int u = __float_as_uint(f);
  u = u + 0x7FFFu + ((u >> 16) & 1u);
  return (u16)(u >> 16);
}
DEVINL float bf2f(u16 h) { return __uint_as_float(((unsigned int)h) << 16); }

DEVINL f4 mfma_(b16x8 a, b16x8 b, f4 c) {
  return __builtin_amdgcn_mfma_f32_16x16x32_bf16(a, b, c, 0, 0, 0);
}
// bf16x3: (ah+al)*(bh+bl) ~= ah*bh + ah*bl + al*bh
DEVINL f4 mfma3(b16x8 ah, b16x8 al, b16x8 bh, b16x8 bl, f4 c) {
  c = mfma_(ah, bh, c);
  c = mfma_(ah, bl, c);
  c = mfma_(al, bh, c);
  return c;
}
DEVINL void gload16(const u16* g, u16* l) {
  __builtin_amdgcn_global_load_lds(
      (const __attribute__((address_space(1))) void*)g,
      (__attribute__((address_space(3))) void*)l, 16, 0, 0);
}

// one-barrier-per-K-step fence: drain this wave's staging loads + LDS ops,
// then block barrier. (ds_read results were already consumed by MFMAs.)
#define PIPE_BARRIER()                                              \
  do {                                                              \
    asm volatile("s_waitcnt vmcnt(0) lgkmcnt(0)" ::: "memory");     \
    __builtin_amdgcn_s_barrier();                                   \
  } while (0)

// ---- GEMM tile helpers: [128][64] bf16 tile, 16B-chunk XOR swizzle
// (round-5-proven). LDS chunk cp holds global chunk (row=cp>>3, j=(cp&7)^(row&7)).
DEVINL void stage_tile(const u16* __restrict__ gbase, int rstride,
                       u16* __restrict__ lds, int t) {
#pragma unroll
  for (int r = 0; r < 4; ++r) {
    int cp = r * 256 + t;                // chunk 0..1023
    int row = cp >> 3, j = cp & 7;
    int jj = j ^ (row & 7);
    gload16(&gbase[(size_t)row * rstride + jj * 8], &lds[cp * 8]);
  }
}
DEVINL b16x8 readfrag(const u16* __restrict__ lds, int row, int kk, int g) {
  int chunk = row * 8 + ((kk * 4 + g) ^ (row & 7));
  return *(const b16x8*)&lds[chunk * 8];
}

// ---------------------------------------------------------------------------
// K0: merged prep.
//  blocks [0,8192):      x fp32 -> bf16 (xh)
//  blocks [8192,8704):   Wk -> wh rows 0..511 (bf16)
//  blocks [8704,8960):   Wb hi/lo split
//  blocks [8960,9280):   64x64 transpose+split: Wa^T, Wq^T, Wv^T
//  blocks [9280,9288):   l[8192] = 0
__global__ __launch_bounds__(256) void k_prep(
    const float* __restrict__ x, const float* __restrict__ Wk,
    const float* __restrict__ Wq, const float* __restrict__ Wv,
    const float* __restrict__ Wa, const float* __restrict__ Wb,
    u16* __restrict__ xh, u16* __restrict__ wh,
    u16* __restrict__ waT_h, u16* __restrict__ waT_l,
    u16* __restrict__ wqT_h, u16* __restrict__ wqT_l,
    u16* __restrict__ wb_h, u16* __restrict__ wb_l,
    u16* __restrict__ wvT_h, u16* __restrict__ wvT_l,
    float* __restrict__ l) {
  const int bid = blockIdx.x, t = threadIdx.x;
  if (bid < 8192) {                      // x -> bf16
    int i = bid * 256 + t;
    float4 v = ((const float4*)x)[i];
    ushort4 h;
    h.x = f2bf(v.x); h.y = f2bf(v.y); h.z = f2bf(v.z); h.w = f2bf(v.w);
    ((ushort4*)xh)[i] = h;
    return;
  }
  if (bid < 8704) {                      // Wk copy
    int i = (bid - 8192) * 256 + t;
    float4 v = ((const float4*)Wk)[i];
    ushort4 h;
    h.x = f2bf(v.x); h.y = f2bf(v.y); h.z = f2bf(v.z); h.w = f2bf(v.w);
    ((ushort4*)wh)[i] = h;
    return;
  }
  if (bid < 8960) {                      // Wb hi/lo split
    int i = (bid - 8704) * 256 + t;
    float4 v = ((const float4*)Wb)[i];
    ushort4 h, lo;
    h.x = f2bf(v.x); lo.x = f2bf(v.x - bf2f(h.x));
    h.y = f2bf(v.y); lo.y = f2bf(v.y - bf2f(h.y));
    h.z = f2bf(v.z); lo.z = f2bf(v.z - bf2f(h.z));
    h.w = f2bf(v.w); lo.w = f2bf(v.w - bf2f(h.w));
    ((ushort4*)wb_h)[i] = h;
    ((ushort4*)wb_l)[i] = lo;
    return;
  }
  if (bid >= 9280) {                     // l = 0
    int i = (bid - 9280) * 256 + t;
    float4 z = {0.f, 0.f, 0.f, 0.f};
    ((float4*)l)[i] = z;
    return;
  }
  // ---- 64x64 tile transpose + hi/lo split
  __shared__ float ftile[64][68];
  const int tb = bid - 8960;             // 0..319
  const float* src;
  u16 *dh, *dl;
  int S, m0, c0;
  if (tb < 64) {                         // Wa [512][512] -> waT
    src = Wa; dh = waT_h; dl = waT_l; S = 512;
    m0 = (tb >> 3) * 64; c0 = (tb & 7) * 64;
  } else if (tb < 192) {                 // Wq [512][1024] -> wqT [1024][512]
    int q = tb - 64;
    src = Wq; dh = wqT_h; dl = wqT_l; S = 1024;
    m0 = (q >> 4) * 64; c0 = (q & 15) * 64;
  } else {                               // Wv [512][1024] -> wvT [1024][512]
    int q = tb - 192;
    src = Wv; dh = wvT_h; dl = wvT_l; S = 1024;
    m0 = (q >> 4) * 64; c0 = (q & 15) * 64;
  }
  {
    int i = t >> 4, j4 = (t & 15) * 4;
#pragma unroll
    for (int ii = 0; ii < 4; ++ii) {
      int row = i + ii * 16;
      float4 v = *(const float4*)&src[(size_t)(m0 + row) * S + c0 + j4];
      ftile[row][j4] = v.x; ftile[row][j4 + 1] = v.y;
      ftile[row][j4 + 2] = v.z; ftile[row][j4 + 3] = v.w;
    }
  }
  __syncthreads();
  {
    int oc = t >> 2, mc = (t & 3) * 16;
#pragma unroll
    for (int j = 0; j < 4; ++j) {
      int m = mc + j * 4;
      float v0 = ftile[m][oc], v1 = ftile[m + 1][oc];
      float v2 = ftile[m + 2][oc], v3 = ftile[m + 3][oc];
      ushort4 h, lo;
      h.x = f2bf(v0); lo.x = f2bf(v0 - bf2f(h.x));
      h.y = f2bf(v1); lo.y = f2bf(v1 - bf2f(h.y));
      h.z = f2bf(v2); lo.z = f2bf(v2 - bf2f(h.z));
      h.w = f2bf(v3); lo.w = f2bf(v3 - bf2f(h.w));
      size_t o = (size_t)(c0 + oc) * 512 + m0 + m;
      *(ushort4*)&dh[o] = h;
      *(ushort4*)&dl[o] = lo;
    }
  }
}

// ---------------------------------------------------------------------------
// K1: fold GEMMs, bf16x3 (round-6-proven, unchanged).
__global__ __launch_bounds__(256, 2) void k_fold_mfma(
    const u16* __restrict__ waT_h, const u16* __restrict__ waT_l,
    const u16* __restrict__ wqT_h, const u16* __restrict__ wqT_l,
    const u16* __restrict__ wb_h, const u16* __restrict__ wb_l,
    const u16* __restrict__ wvT_h, const u16* __restrict__ wvT_l,
    u16* __restrict__ wh) {
  __shared__ u16 lah[8192], lal[8192], lbh[8192], lbl[8192];
  const int blk = blockIdx.x;            // 0..63
  const int which = blk >> 5;            // 0 = Wp, 1 = Wu
  const int idx = blk & 31;
  const int r0 = (idx >> 3) * 128, c0 = (idx & 7) * 128;
  const u16* Ah = which ? wb_h : waT_h;
  const u16* Al = which ? wb_l : waT_l;
  const u16* Bh = which ? wvT_h : wqT_h;
  const u16* Bl = which ? wvT_l : wqT_l;
  const int obase = which ? 1024 : 512;
  const int t = threadIdx.x, lane = t & 63, w = t >> 6;
  const int wr = w >> 1, wc = w & 1, ql = lane & 15, g = lane >> 4;
  const f4 fzero = {0.f, 0.f, 0.f, 0.f};
  f4 acc[4][4];
#pragma unroll
  for (int i = 0; i < 4; ++i)
#pragma unroll
    for (int j = 0; j < 4; ++j) acc[i][j] = fzero;

  for (int ks = 0; ks < 8; ++ks) {       // K = 512
    __syncthreads();
    stage_tile(&Ah[(size_t)r0 * 512 + ks * 64], 512, lah, t);
    stage_tile(&Al[(size_t)r0 * 512 + ks * 64], 512, lal, t);
    stage_tile(&Bh[(size_t)c0 * 512 + ks * 64], 512, lbh, t);
    stage_tile(&Bl[(size_t)c0 * 512 + ks * 64], 512, lbl, t);
    __syncthreads();
#pragma unroll
    for (int kk = 0; kk < 2; ++kk) {
      b16x8 ah[4], al[4], bh[4], bl[4];
#pragma unroll
      for (int rt = 0; rt < 4; ++rt) {
        ah[rt] = readfrag(lah, wr * 64 + rt * 16 + ql, kk, g);
        al[rt] = readfrag(lal, wr * 64 + rt * 16 + ql, kk, g);
      }
#pragma unroll
      for (int ct = 0; ct < 4; ++ct) {
        bh[ct] = readfrag(lbh, wc * 64 + ct * 16 + ql, kk, g);
        bl[ct] = readfrag(lbl, wc * 64 + ct * 16 + ql, kk, g);
      }
#pragma unroll
      for (int rt = 0; rt < 4; ++rt)
#pragma unroll
        for (int ct = 0; ct < 4; ++ct)
          acc[rt][ct] = mfma3(ah[rt], al[rt], bh[ct], bl[ct], acc[rt][ct]);
    }
  }
#pragma unroll
  for (int rt = 0; rt < 4; ++rt) {
#pragma unroll
    for (int ct = 0; ct < 4; ++ct) {
      f4 v = acc[rt][ct];
      int col = c0 + wc * 64 + ct * 16 + ql;
      int rowb = r0 + wr * 64 + rt * 16 + g * 4;
#pragma unroll
      for (int r = 0; r < 4; ++r)
        wh[(size_t)(obase + rowb + r) * 1024 + col] = f2bf(v[r]);
    }
  }
}

// ---------------------------------------------------------------------------
// K2: projection GEMM  Y[8192][1536] = x @ Wcat^T. 1D grid 768, XCD-pinned.
// cb<8 (K,P): operand-swapped -> C[feature][s], ushort4 stores along features.
// cb>=8 (U): C[s][d] -> ut[b][d][k] ushort4 along k.
__global__ __launch_bounds__(256, 2) void k_proj(
    const u16* __restrict__ xh, const u16* __restrict__ wh,
    u16* __restrict__ kh, u16* __restrict__ ph, u16* __restrict__ ut) {
  __shared__ u16 lx[2][8192], lw[2][8192];
  const int bid = blockIdx.x;
  const int cb = bid >> 6;                         // 0..11
  const int rb = (bid & 7) * 8 + ((bid >> 3) & 7); // 0..63, XCD-chunked
  const bool swp = cb < 8;
  const int t = threadIdx.x, lane = t & 63, w = t >> 6;
  const int wr = w >> 1, wc = w & 1, ql = lane & 15, g = lane >> 4;
  const f4 fzero = {0.f, 0.f, 0.f, 0.f};
  f4 acc[4][4];
#pragma unroll
  for (int i = 0; i < 4; ++i)
#pragma unroll
    for (int j = 0; j < 4; ++j) acc[i][j] = fzero;

  const u16* xb = &xh[(size_t)(rb * 128) * 1024];
  const u16* wb = &wh[(size_t)(cb * 128) * 1024];
  stage_tile(xb, 1024, lx[0], t);
  stage_tile(wb, 1024, lw[0], t);
  PIPE_BARRIER();
  for (int ks = 0; ks < 16; ++ks) {
    const int buf = ks & 1;
    if (ks < 15) {
      stage_tile(xb + (ks + 1) * 64, 1024, lx[buf ^ 1], t);
      stage_tile(wb + (ks + 1) * 64, 1024, lw[buf ^ 1], t);
    }
    const u16* As = swp ? lw[buf] : lx[buf];
    const u16* Bs = swp ? lx[buf] : lw[buf];
#pragma unroll
    for (int kk = 0; kk < 2; ++kk) {
      b16x8 ah[4], bh[4];
#pragma unroll
      for (int rt = 0; rt < 4; ++rt)
        ah[rt] = readfrag(As, wr * 64 + rt * 16 + ql, kk, g);
#pragma unroll
      for (int ct = 0; ct < 4; ++ct)
        bh[ct] = readfrag(Bs, wc * 64 + ct * 16 + ql, kk, g);
      __builtin_amdgcn_s_setprio(1);
#pragma unroll
      for (int rt = 0; rt < 4; ++rt)
#pragma unroll
        for (int ct = 0; ct < 4; ++ct)
          acc[rt][ct] = mfma_(ah[rt], bh[ct], acc[rt][ct]);
      __builtin_amdgcn_s_setprio(0);
    }
    PIPE_BARRIER();
  }

  if (swp) {
    // C[f][s]: f = cb*128+wr*64+rt*16+g*4+r, s = rb*128+wc*64+ct*16+ql
#pragma unroll
    for (int rt = 0; rt < 4; ++rt) {
#pragma unroll
      for (int ct = 0; ct < 4; ++ct) {
        f4 v = acc[rt][ct];
        int f = cb * 128 + wr * 64 + rt * 16 + g * 4;
        int s = rb * 128 + wc * 64 + ct * 16 + ql;
        ushort4 hh;
        hh.x = f2bf(v[0]); hh.y = f2bf(v[1]); hh.z = f2bf(v[2]); hh.w = f2bf(v[3]);
        if (cb < 4) *(ushort4*)&kh[(size_t)s * 512 + f] = hh;
        else        *(ushort4*)&ph[(size_t)s * 512 + (f - 512)] = hh;
      }
    }
  } else {
    // C[s][d]: s = rb*128+wr*64+rt*16+g*4+r, d = (cb-8)*128+wc*64+ct*16+ql
#pragma unroll
    for (int rt = 0; rt < 4; ++rt) {
#pragma unroll
      for (int ct = 0; ct < 4; ++ct) {
        f4 v = acc[rt][ct];
        int d = (cb - 8) * 128 + wc * 64 + ct * 16 + ql;
        int rowb = rb * 128 + wr * 64 + rt * 16 + g * 4;
        int bb = rowb >> 11, k0 = rowb & 2047;
        ushort4 hh;
        hh.x = f2bf(v[0]); hh.y = f2bf(v[1]); hh.z = f2bf(v[2]); hh.w = f2bf(v[3]);
        *(ushort4*)&ut[((size_t)bb * 512 + d) * 2048 + k0] = hh;
      }
    }
  }
}

// ---------------------------------------------------------------------------
// K3: score GEMM, operand-swapped: C[k][q] = sum_d K[k][d] P[q][d].
// Epilogue: probs[b][q][k0..k0+3] = exp(C/T) as ushort4; atomic row sums l[q].
__global__ __launch_bounds__(256, 2) void k_score(
    const u16* __restrict__ ph, const u16* __restrict__ kh,
    u16* __restrict__ probs, float* __restrict__ l) {
  constexpr float INVT = 0.04419417382415922f;  // 1/sqrt(512)
  __shared__ u16 lk[2][8192], lp[2][8192];
  const int blk = blockIdx.x;
  const int xcd = blk & 7, half = xcd & 1, b = xcd >> 1;
  const int idx = blk >> 3;                  // 0..127
  const int qtb = idx >> 3;                  // 0..15
  const int ktb = half * 8 + (idx & 7);      // 0..15
  const int q0 = qtb * 128, k0 = ktb * 128;
  const int t = threadIdx.x, lane = t & 63, w = t >> 6;
  const int wr = w >> 1, wc = w & 1, ql = lane & 15, g = lane >> 4;
  const f4 fzero = {0.f, 0.f, 0.f, 0.f};
  f4 acc[4][4];
#pragma unroll
  for (int i = 0; i < 4; ++i)
#pragma unroll
    for (int j = 0; j < 4; ++j) acc[i][j] = fzero;

  const u16* kb = &kh[((size_t)b * 2048 + k0) * 512];
  const u16* pb = &ph[((size_t)b * 2048 + q0) * 512];
  stage_tile(kb, 512, lk[0], t);
  stage_tile(pb, 512, lp[0], t);
  PIPE_BARRIER();
  for (int ks = 0; ks < 8; ++ks) {           // Kd = 512
    const int buf = ks & 1;
    if (ks < 7) {
      stage_tile(kb + (ks + 1) * 64, 512, lk[buf ^ 1], t);
      stage_tile(pb + (ks + 1) * 64, 512, lp[buf ^ 1], t);
    }
#pragma unroll
    for (int kk = 0; kk < 2; ++kk) {
      b16x8 ah[4], bh[4];
#pragma unroll
      for (int rt = 0; rt < 4; ++rt)
        ah[rt] = readfrag(lk[buf], wr * 64 + rt * 16 + ql, kk, g);
#pragma unroll
      for (int ct = 0; ct < 4; ++ct)
        bh[ct] = readfrag(lp[buf], wc * 64 + ct * 16 + ql, kk, g);
      __builtin_amdgcn_s_setprio(1);
#pragma unroll
      for (int rt = 0; rt < 4; ++rt)
#pragma unroll
        for (int ct = 0; ct < 4; ++ct)
          acc[rt][ct] = mfma_(ah[rt], bh[ct], acc[rt][ct]);
      __builtin_amdgcn_s_setprio(0);
    }
    PIPE_BARRIER();
  }

  // epilogue: k-row = k0+wr*64+rt*16+g*4+r, q-col = q0+wc*64+ct*16+ql
  float lq[4] = {0.f, 0.f, 0.f, 0.f};
#pragma unroll
  for (int rt = 0; rt < 4; ++rt) {
    int kb_ = k0 + wr * 64 + rt * 16 + g * 4;
#pragma unroll
    for (int ct = 0; ct < 4; ++ct) {
      int q = q0 + wc * 64 + ct * 16 + ql;
      f4 a = acc[rt][ct];
      float p0 = __expf(a[0] * INVT), p1 = __expf(a[1] * INVT);
      float p2 = __expf(a[2] * INVT), p3 = __expf(a[3] * INVT);
      ushort4 hh;
      hh.x = f2bf(p0); hh.y = f2bf(p1); hh.z = f2bf(p2); hh.w = f2bf(p3);
      *(ushort4*)&probs[((size_t)b * 2048 + q) * 2048 + kb_] = hh;
      lq[ct] += (p0 + p1) + (p2 + p3);
    }
  }
#pragma unroll
  for (int ct = 0; ct < 4; ++ct) {
    float s = lq[ct];
    s += __shfl_xor(s, 16);
    s += __shfl_xor(s, 32);
    if (lane < 16) atomicAdd(&l[b * 2048 + q0 + wc * 64 + ct * 16 + lane], s);
  }
}

// ---------------------------------------------------------------------------
// K4: output GEMM. outT[d][q] = sum_k ut[d][k] probs[q][k]; out[q][d] = v/l[q].
__global__ __launch_bounds__(256, 2) void k_out(
    const u16* __restrict__ ut, const u16* __restrict__ probs,
    const float* __restrict__ l, float* __restrict__ out) {
  __shared__ u16 lu[2][8192], lq[2][8192];
  const int blk = blockIdx.x;
  const int xcd = blk & 7, half = xcd & 1, b = xcd >> 1;
  const int idx = blk >> 3;                  // 0..31
  const int dtb = half * 2 + (idx >> 4);     // 0..3
  const int qtb = idx & 15;                  // 0..15
  const int d0 = dtb * 128, q0 = qtb * 128;
  const int t = threadIdx.x, lane = t & 63, w = t >> 6;
  const int wr = w >> 1, wc = w & 1, ql = lane & 15, g = lane >> 4;
  const f4 fzero = {0.f, 0.f, 0.f, 0.f};
  f4 acc[4][4];
#pragma unroll
  for (int i = 0; i < 4; ++i)
#pragma unroll
    for (int j = 0; j < 4; ++j) acc[i][j] = fzero;

  const u16* ub = &ut[((size_t)b * 512 + d0) * 2048];
  const u16* qb = &probs[((size_t)b * 2048 + q0) * 2048];
  stage_tile(ub, 2048, lu[0], t);
  stage_tile(qb, 2048, lq[0], t);
  PIPE_BARRIER();
  for (int ks = 0; ks < 32; ++ks) {          // Kd = 2048
    const int buf = ks & 1;
    if (ks < 31) {
      stage_tile(ub + (ks + 1) * 64, 2048, lu[buf ^ 1], t);
      stage_tile(qb + (ks + 1) * 64, 2048, lq[buf ^ 1], t);
    }
#pragma unroll
    for (int kk = 0; kk < 2; ++kk) {
      b16x8 ah[4], bh[4];
#pragma unroll
      for (int rt = 0; rt < 4; ++rt)
        ah[rt] = readfrag(lu[buf], wr * 64 + rt * 16 + ql, kk, g);
#pragma unroll
      for (int ct = 0; ct < 4; ++ct)
        bh[ct] = readfrag(lq[buf], wc * 64 + ct * 16 + ql, kk, g);
      __builtin_amdgcn_s_setprio(1);
#pragma unroll
      for (int rt = 0; rt < 4; ++rt)
#pragma unroll
        for (int ct = 0; ct < 4; ++ct)
          acc[rt][ct] = mfma_(ah[rt], bh[ct], acc[rt][ct]);
      __builtin_amdgcn_s_setprio(0);
    }
    PIPE_BARRIER();
  }

  // epilogue: row = d, col = q; out[b][q][d] = v / l[q], float4 stores
#pragma unroll
  for (int ct = 0; ct < 4; ++ct) {
    int q = q0 + wc * 64 + ct * 16 + ql;
    float inv = 1.0f / l[b * 2048 + q];
    size_t orow = ((size_t)b * 2048 + q) * 512;
#pragma unroll
    for (int rt = 0; rt < 4; ++rt) {
      int d = d0 + wr * 64 + rt * 16 + g * 4;
      f4 v = acc[rt][ct] * inv;
      *(f4*)&out[orow + d] = v;
    }
  }
}

// ---------------------------------------------------------------------------
extern "C" void kernel_launch(void* const* d_in, const int* in_sizes, int n_in,
                              void* d_out, int out_size, void* d_ws, size_t ws_size,
                              hipStream_t stream) {
  const float* x = (const float*)d_in[0];
  const float* Wk = (const float*)d_in[1];
  const float* Wq = (const float*)d_in[2];
  const float* Wv = (const float*)d_in[3];
  const float* Wa = (const float*)d_in[4];
  const float* Wb = (const float*)d_in[5];
  float* out = (float*)d_out;

  char* ws = (char*)d_ws;
  size_t off = 0;
  auto alloc = [&](size_t bytes) -> void* {
    void* p = ws + off;
    off += (bytes + 255) & ~(size_t)255;
    return p;
  };
  u16* wh = (u16*)alloc((size_t)1536 * 1024 * 2);
  u16* xh = (u16*)alloc((size_t)8192 * 1024 * 2);
  u16* kh = (u16*)alloc((size_t)8192 * 512 * 2);
  u16* ph = (u16*)alloc((size_t)8192 * 512 * 2);
  u16* ut = (u16*)alloc((size_t)8192 * 512 * 2);
  u16* probs = (u16*)alloc((size_t)4 * 2048 * 2048 * 2);
  float* l = (float*)alloc(8192 * 4);
  u16* waT_h = (u16*)alloc((size_t)512 * 512 * 2);
  u16* waT_l = (u16*)alloc((size_t)512 * 512 * 2);
  u16* wqT_h = (u16*)alloc((size_t)1024 * 512 * 2);
  u16* wqT_l = (u16*)alloc((size_t)1024 * 512 * 2);
  u16* wb_h = (u16*)alloc((size_t)512 * 512 * 2);
  u16* wb_l = (u16*)alloc((size_t)512 * 512 * 2);
  u16* wvT_h = (u16*)alloc((size_t)1024 * 512 * 2);
  u16* wvT_l = (u16*)alloc((size_t)1024 * 512 * 2);
  (void)ws_size; (void)in_sizes; (void)n_in; (void)out_size;

  hipLaunchKernelGGL(k_prep, dim3(9288), dim3(256), 0, stream,
                     x, Wk, Wq, Wv, Wa, Wb, xh, wh,
                     waT_h, waT_l, wqT_h, wqT_l, wb_h, wb_l, wvT_h, wvT_l, l);
  hipLaunchKernelGGL(k_fold_mfma, dim3(64), dim3(256), 0, stream,
                     waT_h, waT_l, wqT_h, wqT_l, wb_h, wb_l, wvT_h, wvT_l, wh);
  hipLaunchKernelGGL(k_proj, dim3(768), dim3(256), 0, stream, xh, wh, kh, ph, ut);
  hipLaunchKernelGGL(k_score, dim3(1024), dim3(256), 0, stream, ph, kh, probs, l);
  hipLaunchKernelGGL(k_out, dim3(256), dim3(256), 0, stream, ut, probs, l, out);
}

// Round 8
// 135.585 us; speedup vs baseline: 1.0041x; 1.0041x over previous
//
#include <hip/hip_runtime.h>

// SelfAttention_33852932227207 — MI355X, round 8.
// e = x^T (Wq^T Wa Wk) x / sqrt(512);  out = softmax(e) @ (x (Wb Wv)^T).
// Round-8: k_proj & k_score -> 256x256 BK=64 8-wave tiles (per-wave 128x64,
// 64 MFMA/K-tile = ~2480-cyc MFMA window >> load latency -> vmcnt(0) drain
// is free; the r7 128^2 window was 620 cyc -> 22% MfmaUtil).
// LDS 128KB dbuf, 1 block/CU. r5-proven chunk-XOR swizzle (bank-conflict=0).
// k_prep / k_fold_mfma / k_out unchanged from round 7.

typedef __attribute__((ext_vector_type(8))) short b16x8;
typedef __attribute__((ext_vector_type(4))) float f4;
typedef unsigned short u16;

#define DEVINL __device__ __forceinline__

DEVINL u16 f2bf(float f) {               // fp32 -> bf16 RNE
  unsigned int u = __float_as_uint(f);
  u = u + 0x7FFFu + ((u >> 16) & 1u);
  return (u16)(u >> 16);
}
DEVINL float bf2f(u16 h) { return __uint_as_float(((unsigned int)h) << 16); }

DEVINL f4 mfma_(b16x8 a, b16x8 b, f4 c) {
  return __builtin_amdgcn_mfma_f32_16x16x32_bf16(a, b, c, 0, 0, 0);
}
// bf16x3: (ah+al)*(bh+bl) ~= ah*bh + ah*bl + al*bh
DEVINL f4 mfma3(b16x8 ah, b16x8 al, b16x8 bh, b16x8 bl, f4 c) {
  c = mfma_(ah, bh, c);
  c = mfma_(ah, bl, c);
  c = mfma_(al, bh, c);
  return c;
}
DEVINL void gload16(const u16* g, u16* l) {
  __builtin_amdgcn_global_load_lds(
      (const __attribute__((address_space(1))) void*)g,
      (__attribute__((address_space(3))) void*)l, 16, 0, 0);
}

#define PIPE_BARRIER()                                              \
  do {                                                              \
    asm volatile("s_waitcnt vmcnt(0) lgkmcnt(0)" ::: "memory");     \
    __builtin_amdgcn_s_barrier();                                   \
  } while (0)

// ---- tile helpers, 16B-chunk XOR swizzle (r5-proven, bank-conflict=0).
// 128-row tile (1024 chunks, 256 thr) and 256-row tile (2048 chunks, 512 thr).
DEVINL void stage_tile(const u16* __restrict__ gbase, int rstride,
                       u16* __restrict__ lds, int t) {
#pragma unroll
  for (int r = 0; r < 4; ++r) {
    int cp = r * 256 + t;
    int row = cp >> 3, j = cp & 7;
    int jj = j ^ (row & 7);
    gload16(&gbase[(size_t)row * rstride + jj * 8], &lds[cp * 8]);
  }
}
DEVINL void stage256(const u16* __restrict__ gbase, int rstride,
                     u16* __restrict__ lds, int t) {
#pragma unroll
  for (int r = 0; r < 4; ++r) {
    int cp = r * 512 + t;                // 0..2047
    int row = cp >> 3, j = cp & 7;
    int jj = j ^ (row & 7);
    gload16(&gbase[(size_t)row * rstride + jj * 8], &lds[cp * 8]);
  }
}
DEVINL b16x8 readfrag(const u16* __restrict__ lds, int row, int kk, int g) {
  int chunk = row * 8 + ((kk * 4 + g) ^ (row & 7));
  return *(const b16x8*)&lds[chunk * 8];
}

// ---------------------------------------------------------------------------
// K0: merged prep (unchanged from r7).
__global__ __launch_bounds__(256) void k_prep(
    const float* __restrict__ x, const float* __restrict__ Wk,
    const float* __restrict__ Wq, const float* __restrict__ Wv,
    const float* __restrict__ Wa, const float* __restrict__ Wb,
    u16* __restrict__ xh, u16* __restrict__ wh,
    u16* __restrict__ waT_h, u16* __restrict__ waT_l,
    u16* __restrict__ wqT_h, u16* __restrict__ wqT_l,
    u16* __restrict__ wb_h, u16* __restrict__ wb_l,
    u16* __restrict__ wvT_h, u16* __restrict__ wvT_l,
    float* __restrict__ l) {
  const int bid = blockIdx.x, t = threadIdx.x;
  if (bid < 8192) {
    int i = bid * 256 + t;
    float4 v = ((const float4*)x)[i];
    ushort4 h;
    h.x = f2bf(v.x); h.y = f2bf(v.y); h.z = f2bf(v.z); h.w = f2bf(v.w);
    ((ushort4*)xh)[i] = h;
    return;
  }
  if (bid < 8704) {
    int i = (bid - 8192) * 256 + t;
    float4 v = ((const float4*)Wk)[i];
    ushort4 h;
    h.x = f2bf(v.x); h.y = f2bf(v.y); h.z = f2bf(v.z); h.w = f2bf(v.w);
    ((ushort4*)wh)[i] = h;
    return;
  }
  if (bid < 8960) {
    int i = (bid - 8704) * 256 + t;
    float4 v = ((const float4*)Wb)[i];
    ushort4 h, lo;
    h.x = f2bf(v.x); lo.x = f2bf(v.x - bf2f(h.x));
    h.y = f2bf(v.y); lo.y = f2bf(v.y - bf2f(h.y));
    h.z = f2bf(v.z); lo.z = f2bf(v.z - bf2f(h.z));
    h.w = f2bf(v.w); lo.w = f2bf(v.w - bf2f(h.w));
    ((ushort4*)wb_h)[i] = h;
    ((ushort4*)wb_l)[i] = lo;
    return;
  }
  if (bid >= 9280) {
    int i = (bid - 9280) * 256 + t;
    float4 z = {0.f, 0.f, 0.f, 0.f};
    ((float4*)l)[i] = z;
    return;
  }
  __shared__ float ftile[64][68];
  const int tb = bid - 8960;
  const float* src;
  u16 *dh, *dl;
  int S, m0, c0;
  if (tb < 64) {
    src = Wa; dh = waT_h; dl = waT_l; S = 512;
    m0 = (tb >> 3) * 64; c0 = (tb & 7) * 64;
  } else if (tb < 192) {
    int q = tb - 64;
    src = Wq; dh = wqT_h; dl = wqT_l; S = 1024;
    m0 = (q >> 4) * 64; c0 = (q & 15) * 64;
  } else {
    int q = tb - 192;
    src = Wv; dh = wvT_h; dl = wvT_l; S = 1024;
    m0 = (q >> 4) * 64; c0 = (q & 15) * 64;
  }
  {
    int i = t >> 4, j4 = (t & 15) * 4;
#pragma unroll
    for (int ii = 0; ii < 4; ++ii) {
      int row = i + ii * 16;
      float4 v = *(const float4*)&src[(size_t)(m0 + row) * S + c0 + j4];
      ftile[row][j4] = v.x; ftile[row][j4 + 1] = v.y;
      ftile[row][j4 + 2] = v.z; ftile[row][j4 + 3] = v.w;
    }
  }
  __syncthreads();
  {
    int oc = t >> 2, mc = (t & 3) * 16;
#pragma unroll
    for (int j = 0; j < 4; ++j) {
      int m = mc + j * 4;
      float v0 = ftile[m][oc], v1 = ftile[m + 1][oc];
      float v2 = ftile[m + 2][oc], v3 = ftile[m + 3][oc];
      ushort4 h, lo;
      h.x = f2bf(v0); lo.x = f2bf(v0 - bf2f(h.x));
      h.y = f2bf(v1); lo.y = f2bf(v1 - bf2f(h.y));
      h.z = f2bf(v2); lo.z = f2bf(v2 - bf2f(h.z));
      h.w = f2bf(v3); lo.w = f2bf(v3 - bf2f(h.w));
      size_t o = (size_t)(c0 + oc) * 512 + m0 + m;
      *(ushort4*)&dh[o] = h;
      *(ushort4*)&dl[o] = lo;
    }
  }
}

// ---------------------------------------------------------------------------
// K1: fold GEMMs, bf16x3 (unchanged from r7).
__global__ __launch_bounds__(256, 2) void k_fold_mfma(
    const u16* __restrict__ waT_h, const u16* __restrict__ waT_l,
    const u16* __restrict__ wqT_h, const u16* __restrict__ wqT_l,
    const u16* __restrict__ wb_h, const u16* __restrict__ wb_l,
    const u16* __restrict__ wvT_h, const u16* __restrict__ wvT_l,
    u16* __restrict__ wh) {
  __shared__ u16 lah[8192], lal[8192], lbh[8192], lbl[8192];
  const int blk = blockIdx.x;
  const int which = blk >> 5;
  const int idx = blk & 31;
  const int r0 = (idx >> 3) * 128, c0 = (idx & 7) * 128;
  const u16* Ah = which ? wb_h : waT_h;
  const u16* Al = which ? wb_l : waT_l;
  const u16* Bh = which ? wvT_h : wqT_h;
  const u16* Bl = which ? wvT_l : wqT_l;
  const int obase = which ? 1024 : 512;
  const int t = threadIdx.x, lane = t & 63, w = t >> 6;
  const int wr = w >> 1, wc = w & 1, ql = lane & 15, g = lane >> 4;
  const f4 fzero = {0.f, 0.f, 0.f, 0.f};
  f4 acc[4][4];
#pragma unroll
  for (int i = 0; i < 4; ++i)
#pragma unroll
    for (int j = 0; j < 4; ++j) acc[i][j] = fzero;

  for (int ks = 0; ks < 8; ++ks) {
    __syncthreads();
    stage_tile(&Ah[(size_t)r0 * 512 + ks * 64], 512, lah, t);
    stage_tile(&Al[(size_t)r0 * 512 + ks * 64], 512, lal, t);
    stage_tile(&Bh[(size_t)c0 * 512 + ks * 64], 512, lbh, t);
    stage_tile(&Bl[(size_t)c0 * 512 + ks * 64], 512, lbl, t);
    __syncthreads();
#pragma unroll
    for (int kk = 0; kk < 2; ++kk) {
      b16x8 ah[4], al[4], bh[4], bl[4];
#pragma unroll
      for (int rt = 0; rt < 4; ++rt) {
        ah[rt] = readfrag(lah, wr * 64 + rt * 16 + ql, kk, g);
        al[rt] = readfrag(lal, wr * 64 + rt * 16 + ql, kk, g);
      }
#pragma unroll
      for (int ct = 0; ct < 4; ++ct) {
        bh[ct] = readfrag(lbh, wc * 64 + ct * 16 + ql, kk, g);
        bl[ct] = readfrag(lbl, wc * 64 + ct * 16 + ql, kk, g);
      }
#pragma unroll
      for (int rt = 0; rt < 4; ++rt)
#pragma unroll
        for (int ct = 0; ct < 4; ++ct)
          acc[rt][ct] = mfma3(ah[rt], al[rt], bh[ct], bl[ct], acc[rt][ct]);
    }
  }
#pragma unroll
  for (int rt = 0; rt < 4; ++rt) {
#pragma unroll
    for (int ct = 0; ct < 4; ++ct) {
      f4 v = acc[rt][ct];
      int col = c0 + wc * 64 + ct * 16 + ql;
      int rowb = r0 + wr * 64 + rt * 16 + g * 4;
#pragma unroll
      for (int r = 0; r < 4; ++r)
        wh[(size_t)(obase + rowb + r) * 1024 + col] = f2bf(v[r]);
    }
  }
}

// ---------------------------------------------------------------------------
// K2: projection GEMM, 256x256 BK=64 8-wave. Grid 192 = 6 f-tiles x 32 s-tiles.
// f-tiles 0..3 (K,P): MFMA A=w-tile -> C[f][s], ushort4 along f.
// f-tiles 4..5 (U):   MFMA A=x-tile -> C[s][f], ushort4 along k into ut[d][k].
__global__ __launch_bounds__(512, 2) void k_proj(
    const u16* __restrict__ xh, const u16* __restrict__ wh,
    u16* __restrict__ kh, u16* __restrict__ ph, u16* __restrict__ ut) {
  __shared__ u16 lx[2][16384], lw[2][16384];   // 256x64 each, 128KB total
  const int bid = blockIdx.x;
  const int sn = (bid & 7) * 4 + ((bid >> 3) & 3);  // 0..31, XCD-chunked
  const int fm = bid >> 5;                          // 0..5
  const bool swp = fm < 4;                          // K/P: A=w; U: A=x
  const int t = threadIdx.x, lane = t & 63, w = t >> 6;
  const int wr = w >> 2, wc = w & 3, ql = lane & 15, g = lane >> 4;
  const f4 fzero = {0.f, 0.f, 0.f, 0.f};
  f4 acc[8][4];
#pragma unroll
  for (int i = 0; i < 8; ++i)
#pragma unroll
    for (int j = 0; j < 4; ++j) acc[i][j] = fzero;

  const u16* xb = &xh[(size_t)(sn * 256) * 1024];
  const u16* wb = &wh[(size_t)(fm * 256) * 1024];
  stage256(xb, 1024, lx[0], t);
  stage256(wb, 1024, lw[0], t);
  PIPE_BARRIER();
  for (int kt = 0; kt < 16; ++kt) {
    const int buf = kt & 1;
    if (kt < 15) {
      stage256(xb + (kt + 1) * 64, 1024, lx[buf ^ 1], t);
      stage256(wb + (kt + 1) * 64, 1024, lw[buf ^ 1], t);
    }
    const u16* As = swp ? lw[buf] : lx[buf];
    const u16* Bs = swp ? lx[buf] : lw[buf];
#pragma unroll
    for (int kk = 0; kk < 2; ++kk) {
      b16x8 af[8], bf[4];
#pragma unroll
      for (int rt = 0; rt < 8; ++rt)
        af[rt] = readfrag(As, wr * 128 + rt * 16 + ql, kk, g);
#pragma unroll
      for (int ct = 0; ct < 4; ++ct)
        bf[ct] = readfrag(Bs, wc * 64 + ct * 16 + ql, kk, g);
      __builtin_amdgcn_s_setprio(1);
#pragma unroll
      for (int rt = 0; rt < 8; ++rt)
#pragma unroll
        for (int ct = 0; ct < 4; ++ct)
          acc[rt][ct] = mfma_(af[rt], bf[ct], acc[rt][ct]);
      __builtin_amdgcn_s_setprio(0);
    }
    PIPE_BARRIER();
  }

  if (swp) {
    // C[f][s]: f = fm*256+wr*128+rt*16+g*4 (+r), s = sn*256+wc*64+ct*16+ql
    const int fblk = fm * 2 + wr;        // 0..7, constant per wave
#pragma unroll
    for (int rt = 0; rt < 8; ++rt) {
#pragma unroll
      for (int ct = 0; ct < 4; ++ct) {
        f4 v = acc[rt][ct];
        int f = fm * 256 + wr * 128 + rt * 16 + g * 4;
        int s = sn * 256 + wc * 64 + ct * 16 + ql;
        ushort4 hh;
        hh.x = f2bf(v[0]); hh.y = f2bf(v[1]); hh.z = f2bf(v[2]); hh.w = f2bf(v[3]);
        if (fblk < 4) *(ushort4*)&kh[(size_t)s * 512 + f] = hh;
        else          *(ushort4*)&ph[(size_t)s * 512 + (f - 512)] = hh;
      }
    }
  } else {
    // C[s][f]: s = sn*256+wr*128+rt*16+g*4 (+r), d = f-1024
#pragma unroll
    for (int rt = 0; rt < 8; ++rt) {
#pragma unroll
      for (int ct = 0; ct < 4; ++ct) {
        f4 v = acc[rt][ct];
        int d = fm * 256 + wc * 64 + ct * 16 + ql - 1024;
        int s = sn * 256 + wr * 128 + rt * 16 + g * 4;
        int bb = s >> 11, k0 = s & 2047;
        ushort4 hh;
        hh.x = f2bf(v[0]); hh.y = f2bf(v[1]); hh.z = f2bf(v[2]); hh.w = f2bf(v[3]);
        *(ushort4*)&ut[((size_t)bb * 512 + d) * 2048 + k0] = hh;
      }
    }
  }
}

// ---------------------------------------------------------------------------
// K3: score GEMM, 256x256 BK=64 8-wave, grid 256 (1/CU). A=K-rows -> C[k][q].
// Epilogue: probs[b][q][k..k+3] = exp(C/T) ushort4; atomic row sums l[q].
__global__ __launch_bounds__(512, 2) void k_score(
    const u16* __restrict__ ph, const u16* __restrict__ kh,
    u16* __restrict__ probs, float* __restrict__ l) {
  constexpr float INVT = 0.04419417382415922f;  // 1/sqrt(512)
  __shared__ u16 lk[2][16384], lp[2][16384];
  const int bid = blockIdx.x;
  const int xcd = bid & 7, b = xcd >> 1, khalf = xcd & 1;
  const int idx = bid >> 3;                  // 0..31
  const int qtb = idx >> 2;                  // 0..7
  const int ktb = khalf * 4 + (idx & 3);     // 0..7
  const int q0 = qtb * 256, k0 = ktb * 256;
  const int t = threadIdx.x, lane = t & 63, w = t >> 6;
  const int wr = w >> 2, wc = w & 3, ql = lane & 15, g = lane >> 4;
  const f4 fzero = {0.f, 0.f, 0.f, 0.f};
  f4 acc[8][4];
#pragma unroll
  for (int i = 0; i < 8; ++i)
#pragma unroll
    for (int j = 0; j < 4; ++j) acc[i][j] = fzero;

  const u16* kb = &kh[((size_t)b * 2048 + k0) * 512];
  const u16* pb = &ph[((size_t)b * 2048 + q0) * 512];
  stage256(kb, 512, lk[0], t);
  stage256(pb, 512, lp[0], t);
  PIPE_BARRIER();
  for (int kt = 0; kt < 8; ++kt) {           // Kd = 512
    const int buf = kt & 1;
    if (kt < 7) {
      stage256(kb + (kt + 1) * 64, 512, lk[buf ^ 1], t);
      stage256(pb + (kt + 1) * 64, 512, lp[buf ^ 1], t);
    }
#pragma unroll
    for (int kk = 0; kk < 2; ++kk) {
      b16x8 af[8], bf[4];
#pragma unroll
      for (int rt = 0; rt < 8; ++rt)
        af[rt] = readfrag(lk[buf], wr * 128 + rt * 16 + ql, kk, g);
#pragma unroll
      for (int ct = 0; ct < 4; ++ct)
        bf[ct] = readfrag(lp[buf], wc * 64 + ct * 16 + ql, kk, g);
      __builtin_amdgcn_s_setprio(1);
#pragma unroll
      for (int rt = 0; rt < 8; ++rt)
#pragma unroll
        for (int ct = 0; ct < 4; ++ct)
          acc[rt][ct] = mfma_(af[rt], bf[ct], acc[rt][ct]);
      __builtin_amdgcn_s_setprio(0);
    }
    PIPE_BARRIER();
  }

  // epilogue: k = k0+wr*128+rt*16+g*4 (+r), q = q0+wc*64+ct*16+ql
  float lq[4] = {0.f, 0.f, 0.f, 0.f};
#pragma unroll
  for (int rt = 0; rt < 8; ++rt) {
    int kr = k0 + wr * 128 + rt * 16 + g * 4;
#pragma unroll
    for (int ct = 0; ct < 4; ++ct) {
      int q = q0 + wc * 64 + ct * 16 + ql;
      f4 a = acc[rt][ct];
      float p0 = __expf(a[0] * INVT), p1 = __expf(a[1] * INVT);
      float p2 = __expf(a[2] * INVT), p3 = __expf(a[3] * INVT);
      ushort4 hh;
      hh.x = f2bf(p0); hh.y = f2bf(p1); hh.z = f2bf(p2); hh.w = f2bf(p3);
      *(ushort4*)&probs[((size_t)b * 2048 + q) * 2048 + kr] = hh;
      lq[ct] += (p0 + p1) + (p2 + p3);
    }
  }
#pragma unroll
  for (int ct = 0; ct < 4; ++ct) {
    float s = lq[ct];
    s += __shfl_xor(s, 16);
    s += __shfl_xor(s, 32);
    if (lane < 16) atomicAdd(&l[b * 2048 + q0 + wc * 64 + ct * 16 + lane], s);
  }
}

// ---------------------------------------------------------------------------
// K4: output GEMM (unchanged from r7). outT[d][q] = sum_k ut[d][k] probs[q][k].
__global__ __launch_bounds__(256, 2) void k_out(
    const u16* __restrict__ ut, const u16* __restrict__ probs,
    const float* __restrict__ l, float* __restrict__ out) {
  __shared__ u16 lu[2][8192], lq[2][8192];
  const int blk = blockIdx.x;
  const int xcd = blk & 7, half = xcd & 1, b = xcd >> 1;
  const int idx = blk >> 3;
  const int dtb = half * 2 + (idx >> 4);
  const int qtb = idx & 15;
  const int d0 = dtb * 128, q0 = qtb * 128;
  const int t = threadIdx.x, lane = t & 63, w = t >> 6;
  const int wr = w >> 1, wc = w & 1, ql = lane & 15, g = lane >> 4;
  const f4 fzero = {0.f, 0.f, 0.f, 0.f};
  f4 acc[4][4];
#pragma unroll
  for (int i = 0; i < 4; ++i)
#pragma unroll
    for (int j = 0; j < 4; ++j) acc[i][j] = fzero;

  const u16* ub = &ut[((size_t)b * 512 + d0) * 2048];
  const u16* qb = &probs[((size_t)b * 2048 + q0) * 2048];
  stage_tile(ub, 2048, lu[0], t);
  stage_tile(qb, 2048, lq[0], t);
  PIPE_BARRIER();
  for (int ks = 0; ks < 32; ++ks) {
    const int buf = ks & 1;
    if (ks < 31) {
      stage_tile(ub + (ks + 1) * 64, 2048, lu[buf ^ 1], t);
      stage_tile(qb + (ks + 1) * 64, 2048, lq[buf ^ 1], t);
    }
#pragma unroll
    for (int kk = 0; kk < 2; ++kk) {
      b16x8 ah[4], bh[4];
#pragma unroll
      for (int rt = 0; rt < 4; ++rt)
        ah[rt] = readfrag(lu[buf], wr * 64 + rt * 16 + ql, kk, g);
#pragma unroll
      for (int ct = 0; ct < 4; ++ct)
        bh[ct] = readfrag(lq[buf], wc * 64 + ct * 16 + ql, kk, g);
      __builtin_amdgcn_s_setprio(1);
#pragma unroll
      for (int rt = 0; rt < 4; ++rt)
#pragma unroll
        for (int ct = 0; ct < 4; ++ct)
          acc[rt][ct] = mfma_(ah[rt], bh[ct], acc[rt][ct]);
      __builtin_amdgcn_s_setprio(0);
    }
    PIPE_BARRIER();
  }

#pragma unroll
  for (int ct = 0; ct < 4; ++ct) {
    int q = q0 + wc * 64 + ct * 16 + ql;
    float inv = 1.0f / l[b * 2048 + q];
    size_t orow = ((size_t)b * 2048 + q) * 512;
#pragma unroll
    for (int rt = 0; rt < 4; ++rt) {
      int d = d0 + wr * 64 + rt * 16 + g * 4;
      f4 v = acc[rt][ct] * inv;
      *(f4*)&out[orow + d] = v;
    }
  }
}

// ---------------------------------------------------------------------------
extern "C" void kernel_launch(void* const* d_in, const int* in_sizes, int n_in,
                              void* d_out, int out_size, void* d_ws, size_t ws_size,
                              hipStream_t stream) {
  const float* x = (const float*)d_in[0];
  const float* Wk = (const float*)d_in[1];
  const float* Wq = (const float*)d_in[2];
  const float* Wv = (const float*)d_in[3];
  const float* Wa = (const float*)d_in[4];
  const float* Wb = (const float*)d_in[5];
  float* out = (float*)d_out;

  char* ws = (char*)d_ws;
  size_t off = 0;
  auto alloc = [&](size_t bytes) -> void* {
    void* p = ws + off;
    off += (bytes + 255) & ~(size_t)255;
    return p;
  };
  u16* wh = (u16*)alloc((size_t)1536 * 1024 * 2);
  u16* xh = (u16*)alloc((size_t)8192 * 1024 * 2);
  u16* kh = (u16*)alloc((size_t)8192 * 512 * 2);
  u16* ph = (u16*)alloc((size_t)8192 * 512 * 2);
  u16* ut = (u16*)alloc((size_t)8192 * 512 * 2);
  u16* probs = (u16*)alloc((size_t)4 * 2048 * 2048 * 2);
  float* l = (float*)alloc(8192 * 4);
  u16* waT_h = (u16*)alloc((size_t)512 * 512 * 2);
  u16* waT_l = (u16*)alloc((size_t)512 * 512 * 2);
  u16* wqT_h = (u16*)alloc((size_t)1024 * 512 * 2);
  u16* wqT_l = (u16*)alloc((size_t)1024 * 512 * 2);
  u16* wb_h = (u16*)alloc((size_t)512 * 512 * 2);
  u16* wb_l = (u16*)alloc((size_t)512 * 512 * 2);
  u16* wvT_h = (u16*)alloc((size_t)1024 * 512 * 2);
  u16* wvT_l = (u16*)alloc((size_t)1024 * 512 * 2);
  (void)ws_size; (void)in_sizes; (void)n_in; (void)out_size;

  hipLaunchKernelGGL(k_prep, dim3(9288), dim3(256), 0, stream,
                     x, Wk, Wq, Wv, Wa, Wb, xh, wh,
                     waT_h, waT_l, wqT_h, wqT_l, wb_h, wb_l, wvT_h, wvT_l, l);
  hipLaunchKernelGGL(k_fold_mfma, dim3(64), dim3(256), 0, stream,
                     waT_h, waT_l, wqT_h, wqT_l, wb_h, wb_l, wvT_h, wvT_l, wh);
  hipLaunchKernelGGL(k_proj, dim3(192), dim3(512), 0, stream, xh, wh, kh, ph, ut);
  hipLaunchKernelGGL(k_score, dim3(256), dim3(512), 0, stream, ph, kh, probs, l);
  hipLaunchKernelGGL(k_out, dim3(256), dim3(256), 0, stream, ut, probs, l, out);
}

// Round 9
// 134.926 us; speedup vs baseline: 1.0090x; 1.0049x over previous
//
#include <hip/hip_runtime.h>

// SelfAttention_33852932227207 — MI355X, round 9.
// e = x^T (Wq^T Wa Wk) x / sqrt(512);  out = softmax(e) @ (x (Wb Wv)^T).
// Round-9: k_proj & k_score -> m201-style 8-phase counted-vmcnt schedule
// (4 phases per 256x256xBK=64 K-tile, vmcnt(2) at tile boundary only, stage
// slots 4 phases ahead, setprio around MFMA clusters). The r8 2-phase
// structure measured 586 TF = the known 2-phase ceiling (m233).
// k_prep / k_fold_mfma / k_out unchanged.

typedef __attribute__((ext_vector_type(8))) short b16x8;
typedef __attribute__((ext_vector_type(4))) float f4;
typedef unsigned short u16;

#define DEVINL __device__ __forceinline__

DEVINL u16 f2bf(float f) {               // fp32 -> bf16 RNE
  unsigned int u = __float_as_uint(f);
  u = u + 0x7FFFu + ((u >> 16) & 1u);
  return (u16)(u >> 16);
}
DEVINL float bf2f(u16 h) { return __uint_as_float(((unsigned int)h) << 16); }

DEVINL f4 mfma_(b16x8 a, b16x8 b, f4 c) {
  return __builtin_amdgcn_mfma_f32_16x16x32_bf16(a, b, c, 0, 0, 0);
}
// bf16x3: (ah+al)*(bh+bl) ~= ah*bh + ah*bl + al*bh
DEVINL f4 mfma3(b16x8 ah, b16x8 al, b16x8 bh, b16x8 bl, f4 c) {
  c = mfma_(ah, bh, c);
  c = mfma_(ah, bl, c);
  c = mfma_(al, bh, c);
  return c;
}
DEVINL void gload16(const u16* g, u16* l) {
  __builtin_amdgcn_global_load_lds(
      (const __attribute__((address_space(1))) void*)g,
      (__attribute__((address_space(3))) void*)l, 16, 0, 0);
}

#define PIPE_BARRIER()                                              \
  do {                                                              \
    asm volatile("s_waitcnt vmcnt(0) lgkmcnt(0)" ::: "memory");     \
    __builtin_amdgcn_s_barrier();                                   \
  } while (0)

// ---- tile helpers, 16B-chunk XOR swizzle (r5-proven, bank-conflict=0).
DEVINL void stage_tile(const u16* __restrict__ gbase, int rstride,
                       u16* __restrict__ lds, int t) {
#pragma unroll
  for (int r = 0; r < 4; ++r) {
    int cp = r * 256 + t;
    int row = cp >> 3, j = cp & 7;
    int jj = j ^ (row & 7);
    gload16(&gbase[(size_t)row * rstride + jj * 8], &lds[cp * 8]);
  }
}
// stage one half (128 rows) of a 256x64 tile: 2 gloads/thread (512 thr).
DEVINL void stage_half(const u16* __restrict__ gbase, int rstride,
                       u16* __restrict__ lds, int half, int t) {
#pragma unroll
  for (int r = 0; r < 2; ++r) {
    int cp = half * 1024 + r * 512 + t;   // chunk 0..2047
    int row = cp >> 3, j = cp & 7;
    int jj = j ^ (row & 7);
    gload16(&gbase[(size_t)row * rstride + jj * 8], &lds[cp * 8]);
  }
}
DEVINL b16x8 readfrag(const u16* __restrict__ lds, int row, int kk, int g) {
  int chunk = row * 8 + ((kk * 4 + g) ^ (row & 7));
  return *(const b16x8*)&lds[chunk * 8];
}

// ---- 8-phase 256x256 GEMM core (m201 port). 8 waves (2Mx4N), per-wave
// 128x64 C = acc[8][4]. NT K-tiles of BK=64. ldsA/ldsB: [2][16384] u16.
// Stage slots for tile T+1: {T-1.P3: A-h0, T.P0: A-h1, T.P1: B-h0, T.P2: B-h1}.
// Buffer cur fully consumed after P2 (af1 last read) -> slots write released
// regions only. Boundary vmcnt(2) = allow T+2's A-h0 (2 loads) in flight.
DEVINL void gemm256_8ph(const u16* __restrict__ Ab, int sA,
                        const u16* __restrict__ Bb, int sB, int NT,
                        u16* __restrict__ ldsA, u16* __restrict__ ldsB,
                        int t, int wr, int wc, int ql, int g, f4 acc[8][4]) {
  // prologue: tile0 (4 halves) into buf0, tile1 A-h0 into buf1
  stage_half(Ab, sA, ldsA, 0, t);
  stage_half(Ab, sA, ldsA, 1, t);
  stage_half(Bb, sB, ldsB, 0, t);
  stage_half(Bb, sB, ldsB, 1, t);
  stage_half(Ab + 64, sA, ldsA + 16384, 0, t);
  asm volatile("s_waitcnt vmcnt(2)" ::: "memory");
  __builtin_amdgcn_s_barrier();

  for (int T = 0; T < NT; ++T) {
    const int cur = (T & 1) << 14, nxt = cur ^ 16384;
    const u16* An = Ab + (T + 1) * 64;
    const u16* Bn = Bb + (T + 1) * 64;
    b16x8 af0[8], af1[8], bf0[4], bf1[4];
    // ---- P0: rd af0+bf0 ; stage T+1.A-h1 ; mfma kk0 x n0-1
#pragma unroll
    for (int rt = 0; rt < 8; ++rt)
      af0[rt] = readfrag(ldsA + cur, wr * 128 + rt * 16 + ql, 0, g);
#pragma unroll
    for (int ct = 0; ct < 4; ++ct)
      bf0[ct] = readfrag(ldsB + cur, wc * 64 + ct * 16 + ql, 0, g);
    if (T + 1 < NT) stage_half(An, sA, ldsA + nxt, 1, t);
    __builtin_amdgcn_s_barrier();
    asm volatile("s_waitcnt lgkmcnt(0)" ::: "memory");
    __builtin_amdgcn_s_setprio(1);
#pragma unroll
    for (int rt = 0; rt < 8; ++rt) {
      acc[rt][0] = mfma_(af0[rt], bf0[0], acc[rt][0]);
      acc[rt][1] = mfma_(af0[rt], bf0[1], acc[rt][1]);
    }
    __builtin_amdgcn_s_setprio(0);
    __builtin_amdgcn_s_barrier();
    // ---- P1: rd bf1 ; stage T+1.B-h0 ; mfma kk0 x n2-3
#pragma unroll
    for (int ct = 0; ct < 4; ++ct)
      bf1[ct] = readfrag(ldsB + cur, wc * 64 + ct * 16 + ql, 1, g);
    if (T + 1 < NT) stage_half(Bn, sB, ldsB + nxt, 0, t);
    __builtin_amdgcn_s_barrier();
    asm volatile("s_waitcnt lgkmcnt(0)" ::: "memory");
    __builtin_amdgcn_s_setprio(1);
#pragma unroll
    for (int rt = 0; rt < 8; ++rt) {
      acc[rt][2] = mfma_(af0[rt], bf0[2], acc[rt][2]);
      acc[rt][3] = mfma_(af0[rt], bf0[3], acc[rt][3]);
    }
    __builtin_amdgcn_s_setprio(0);
    __builtin_amdgcn_s_barrier();
    // ---- P2: rd af1 ; stage T+1.B-h1 ; mfma kk1 x n0-1
#pragma unroll
    for (int rt = 0; rt < 8; ++rt)
      af1[rt] = readfrag(ldsA + cur, wr * 128 + rt * 16 + ql, 1, g);
    if (T + 1 < NT) stage_half(Bn, sB, ldsB + nxt, 1, t);
    __builtin_amdgcn_s_barrier();
    asm volatile("s_waitcnt lgkmcnt(0)" ::: "memory");
    __builtin_amdgcn_s_setprio(1);
#pragma unroll
    for (int rt = 0; rt < 8; ++rt) {
      acc[rt][0] = mfma_(af1[rt], bf1[0], acc[rt][0]);
      acc[rt][1] = mfma_(af1[rt], bf1[1], acc[rt][1]);
    }
    __builtin_amdgcn_s_setprio(0);
    __builtin_amdgcn_s_barrier();
    // ---- P3: stage T+2.A-h0 into cur (released after P2) ; mfma kk1 x n2-3
    if (T + 2 < NT) stage_half(Ab + (T + 2) * 64, sA, ldsA + cur, 0, t);
    __builtin_amdgcn_s_barrier();
    __builtin_amdgcn_s_setprio(1);
#pragma unroll
    for (int rt = 0; rt < 8; ++rt) {
      acc[rt][2] = mfma_(af1[rt], bf1[2], acc[rt][2]);
      acc[rt][3] = mfma_(af1[rt], bf1[3], acc[rt][3]);
    }
    __builtin_amdgcn_s_setprio(0);
    if (T < NT - 2) {
      asm volatile("s_waitcnt vmcnt(2)" ::: "memory");  // T+1 drained, T+2.A-h0 flies
    } else {
      asm volatile("s_waitcnt vmcnt(0)" ::: "memory");  // tail: drain fully
    }
    __builtin_amdgcn_s_barrier();
  }
}

// ---------------------------------------------------------------------------
// K0: merged prep (unchanged).
__global__ __launch_bounds__(256) void k_prep(
    const float* __restrict__ x, const float* __restrict__ Wk,
    const float* __restrict__ Wq, const float* __restrict__ Wv,
    const float* __restrict__ Wa, const float* __restrict__ Wb,
    u16* __restrict__ xh, u16* __restrict__ wh,
    u16* __restrict__ waT_h, u16* __restrict__ waT_l,
    u16* __restrict__ wqT_h, u16* __restrict__ wqT_l,
    u16* __restrict__ wb_h, u16* __restrict__ wb_l,
    u16* __restrict__ wvT_h, u16* __restrict__ wvT_l,
    float* __restrict__ l) {
  const int bid = blockIdx.x, t = threadIdx.x;
  if (bid < 8192) {
    int i = bid * 256 + t;
    float4 v = ((const float4*)x)[i];
    ushort4 h;
    h.x = f2bf(v.x); h.y = f2bf(v.y); h.z = f2bf(v.z); h.w = f2bf(v.w);
    ((ushort4*)xh)[i] = h;
    return;
  }
  if (bid < 8704) {
    int i = (bid - 8192) * 256 + t;
    float4 v = ((const float4*)Wk)[i];
    ushort4 h;
    h.x = f2bf(v.x); h.y = f2bf(v.y); h.z = f2bf(v.z); h.w = f2bf(v.w);
    ((ushort4*)wh)[i] = h;
    return;
  }
  if (bid < 8960) {
    int i = (bid - 8704) * 256 + t;
    float4 v = ((const float4*)Wb)[i];
    ushort4 h, lo;
    h.x = f2bf(v.x); lo.x = f2bf(v.x - bf2f(h.x));
    h.y = f2bf(v.y); lo.y = f2bf(v.y - bf2f(h.y));
    h.z = f2bf(v.z); lo.z = f2bf(v.z - bf2f(h.z));
    h.w = f2bf(v.w); lo.w = f2bf(v.w - bf2f(h.w));
    ((ushort4*)wb_h)[i] = h;
    ((ushort4*)wb_l)[i] = lo;
    return;
  }
  if (bid >= 9280) {
    int i = (bid - 9280) * 256 + t;
    float4 z = {0.f, 0.f, 0.f, 0.f};
    ((float4*)l)[i] = z;
    return;
  }
  __shared__ float ftile[64][68];
  const int tb = bid - 8960;
  const float* src;
  u16 *dh, *dl;
  int S, m0, c0;
  if (tb < 64) {
    src = Wa; dh = waT_h; dl = waT_l; S = 512;
    m0 = (tb >> 3) * 64; c0 = (tb & 7) * 64;
  } else if (tb < 192) {
    int q = tb - 64;
    src = Wq; dh = wqT_h; dl = wqT_l; S = 1024;
    m0 = (q >> 4) * 64; c0 = (q & 15) * 64;
  } else {
    int q = tb - 192;
    src = Wv; dh = wvT_h; dl = wvT_l; S = 1024;
    m0 = (q >> 4) * 64; c0 = (q & 15) * 64;
  }
  {
    int i = t >> 4, j4 = (t & 15) * 4;
#pragma unroll
    for (int ii = 0; ii < 4; ++ii) {
      int row = i + ii * 16;
      float4 v = *(const float4*)&src[(size_t)(m0 + row) * S + c0 + j4];
      ftile[row][j4] = v.x; ftile[row][j4 + 1] = v.y;
      ftile[row][j4 + 2] = v.z; ftile[row][j4 + 3] = v.w;
    }
  }
  __syncthreads();
  {
    int oc = t >> 2, mc = (t & 3) * 16;
#pragma unroll
    for (int j = 0; j < 4; ++j) {
      int m = mc + j * 4;
      float v0 = ftile[m][oc], v1 = ftile[m + 1][oc];
      float v2 = ftile[m + 2][oc], v3 = ftile[m + 3][oc];
      ushort4 h, lo;
      h.x = f2bf(v0); lo.x = f2bf(v0 - bf2f(h.x));
      h.y = f2bf(v1); lo.y = f2bf(v1 - bf2f(h.y));
      h.z = f2bf(v2); lo.z = f2bf(v2 - bf2f(h.z));
      h.w = f2bf(v3); lo.w = f2bf(v3 - bf2f(h.w));
      size_t o = (size_t)(c0 + oc) * 512 + m0 + m;
      *(ushort4*)&dh[o] = h;
      *(ushort4*)&dl[o] = lo;
    }
  }
}

// ---------------------------------------------------------------------------
// K1: fold GEMMs, bf16x3 (unchanged).
__global__ __launch_bounds__(256, 2) void k_fold_mfma(
    const u16* __restrict__ waT_h, const u16* __restrict__ waT_l,
    const u16* __restrict__ wqT_h, const u16* __restrict__ wqT_l,
    const u16* __restrict__ wb_h, const u16* __restrict__ wb_l,
    const u16* __restrict__ wvT_h, const u16* __restrict__ wvT_l,
    u16* __restrict__ wh) {
  __shared__ u16 lah[8192], lal[8192], lbh[8192], lbl[8192];
  const int blk = blockIdx.x;
  const int which = blk >> 5;
  const int idx = blk & 31;
  const int r0 = (idx >> 3) * 128, c0 = (idx & 7) * 128;
  const u16* Ah = which ? wb_h : waT_h;
  const u16* Al = which ? wb_l : waT_l;
  const u16* Bh = which ? wvT_h : wqT_h;
  const u16* Bl = which ? wvT_l : wqT_l;
  const int obase = which ? 1024 : 512;
  const int t = threadIdx.x, lane = t & 63, w = t >> 6;
  const int wr = w >> 1, wc = w & 1, ql = lane & 15, g = lane >> 4;
  const f4 fzero = {0.f, 0.f, 0.f, 0.f};
  f4 acc[4][4];
#pragma unroll
  for (int i = 0; i < 4; ++i)
#pragma unroll
    for (int j = 0; j < 4; ++j) acc[i][j] = fzero;

  for (int ks = 0; ks < 8; ++ks) {
    __syncthreads();
    stage_tile(&Ah[(size_t)r0 * 512 + ks * 64], 512, lah, t);
    stage_tile(&Al[(size_t)r0 * 512 + ks * 64], 512, lal, t);
    stage_tile(&Bh[(size_t)c0 * 512 + ks * 64], 512, lbh, t);
    stage_tile(&Bl[(size_t)c0 * 512 + ks * 64], 512, lbl, t);
    __syncthreads();
#pragma unroll
    for (int kk = 0; kk < 2; ++kk) {
      b16x8 ah[4], al[4], bh[4], bl[4];
#pragma unroll
      for (int rt = 0; rt < 4; ++rt) {
        ah[rt] = readfrag(lah, wr * 64 + rt * 16 + ql, kk, g);
        al[rt] = readfrag(lal, wr * 64 + rt * 16 + ql, kk, g);
      }
#pragma unroll
      for (int ct = 0; ct < 4; ++ct) {
        bh[ct] = readfrag(lbh, wc * 64 + ct * 16 + ql, kk, g);
        bl[ct] = readfrag(lbl, wc * 64 + ct * 16 + ql, kk, g);
      }
#pragma unroll
      for (int rt = 0; rt < 4; ++rt)
#pragma unroll
        for (int ct = 0; ct < 4; ++ct)
          acc[rt][ct] = mfma3(ah[rt], al[rt], bh[ct], bl[ct], acc[rt][ct]);
    }
  }
#pragma unroll
  for (int rt = 0; rt < 4; ++rt) {
#pragma unroll
    for (int ct = 0; ct < 4; ++ct) {
      f4 v = acc[rt][ct];
      int col = c0 + wc * 64 + ct * 16 + ql;
      int rowb = r0 + wr * 64 + rt * 16 + g * 4;
#pragma unroll
      for (int r = 0; r < 4; ++r)
        wh[(size_t)(obase + rowb + r) * 1024 + col] = f2bf(v[r]);
    }
  }
}

// ---------------------------------------------------------------------------
// K2: projection GEMM, 256x256 8-phase. Grid 192 = 6 f-tiles x 32 s-tiles.
__global__ __launch_bounds__(512, 2) void k_proj(
    const u16* __restrict__ xh, const u16* __restrict__ wh,
    u16* __restrict__ kh, u16* __restrict__ ph, u16* __restrict__ ut) {
  __shared__ u16 lA[2 * 16384], lB[2 * 16384];   // 128 KB
  const int bid = blockIdx.x;
  const int sn = (bid & 7) * 4 + ((bid >> 3) & 3);  // 0..31, XCD-chunked
  const int fm = bid >> 5;                          // 0..5
  const bool swp = fm < 4;                          // K/P: A=w; U: A=x
  const int t = threadIdx.x, lane = t & 63, w = t >> 6;
  const int wr = w >> 2, wc = w & 3, ql = lane & 15, g = lane >> 4;
  const f4 fzero = {0.f, 0.f, 0.f, 0.f};
  f4 acc[8][4];
#pragma unroll
  for (int i = 0; i < 8; ++i)
#pragma unroll
    for (int j = 0; j < 4; ++j) acc[i][j] = fzero;

  const u16* xb = &xh[(size_t)(sn * 256) * 1024];
  const u16* wb = &wh[(size_t)(fm * 256) * 1024];
  gemm256_8ph(swp ? wb : xb, 1024, swp ? xb : wb, 1024, 16,
              lA, lB, t, wr, wc, ql, g, acc);

  if (swp) {
    const int fblk = fm * 2 + wr;
#pragma unroll
    for (int rt = 0; rt < 8; ++rt) {
#pragma unroll
      for (int ct = 0; ct < 4; ++ct) {
        f4 v = acc[rt][ct];
        int f = fm * 256 + wr * 128 + rt * 16 + g * 4;
        int s = sn * 256 + wc * 64 + ct * 16 + ql;
        ushort4 hh;
        hh.x = f2bf(v[0]); hh.y = f2bf(v[1]); hh.z = f2bf(v[2]); hh.w = f2bf(v[3]);
        if (fblk < 4) *(ushort4*)&kh[(size_t)s * 512 + f] = hh;
        else          *(ushort4*)&ph[(size_t)s * 512 + (f - 512)] = hh;
      }
    }
  } else {
#pragma unroll
    for (int rt = 0; rt < 8; ++rt) {
#pragma unroll
      for (int ct = 0; ct < 4; ++ct) {
        f4 v = acc[rt][ct];
        int d = fm * 256 + wc * 64 + ct * 16 + ql - 1024;
        int s = sn * 256 + wr * 128 + rt * 16 + g * 4;
        int bb = s >> 11, k0 = s & 2047;
        ushort4 hh;
        hh.x = f2bf(v[0]); hh.y = f2bf(v[1]); hh.z = f2bf(v[2]); hh.w = f2bf(v[3]);
        *(ushort4*)&ut[((size_t)bb * 512 + d) * 2048 + k0] = hh;
      }
    }
  }
}

// ---------------------------------------------------------------------------
// K3: score GEMM, 256x256 8-phase, grid 256 (1/CU). A=K-rows -> C[k][q].
__global__ __launch_bounds__(512, 2) void k_score(
    const u16* __restrict__ ph, const u16* __restrict__ kh,
    u16* __restrict__ probs, float* __restrict__ l) {
  constexpr float INVT = 0.04419417382415922f;  // 1/sqrt(512)
  __shared__ u16 lA[2 * 16384], lB[2 * 16384];
  const int bid = blockIdx.x;
  const int xcd = bid & 7, b = xcd >> 1, khalf = xcd & 1;
  const int idx = bid >> 3;                  // 0..31
  const int qtb = idx >> 2;                  // 0..7
  const int ktb = khalf * 4 + (idx & 3);     // 0..7
  const int q0 = qtb * 256, k0 = ktb * 256;
  const int t = threadIdx.x, lane = t & 63, w = t >> 6;
  const int wr = w >> 2, wc = w & 3, ql = lane & 15, g = lane >> 4;
  const f4 fzero = {0.f, 0.f, 0.f, 0.f};
  f4 acc[8][4];
#pragma unroll
  for (int i = 0; i < 8; ++i)
#pragma unroll
    for (int j = 0; j < 4; ++j) acc[i][j] = fzero;

  const u16* kb = &kh[((size_t)b * 2048 + k0) * 512];
  const u16* pb = &ph[((size_t)b * 2048 + q0) * 512];
  gemm256_8ph(kb, 512, pb, 512, 8, lA, lB, t, wr, wc, ql, g, acc);

  float lq[4] = {0.f, 0.f, 0.f, 0.f};
#pragma unroll
  for (int rt = 0; rt < 8; ++rt) {
    int kr = k0 + wr * 128 + rt * 16 + g * 4;
#pragma unroll
    for (int ct = 0; ct < 4; ++ct) {
      int q = q0 + wc * 64 + ct * 16 + ql;
      f4 a = acc[rt][ct];
      float p0 = __expf(a[0] * INVT), p1 = __expf(a[1] * INVT);
      float p2 = __expf(a[2] * INVT), p3 = __expf(a[3] * INVT);
      ushort4 hh;
      hh.x = f2bf(p0); hh.y = f2bf(p1); hh.z = f2bf(p2); hh.w = f2bf(p3);
      *(ushort4*)&probs[((size_t)b * 2048 + q) * 2048 + kr] = hh;
      lq[ct] += (p0 + p1) + (p2 + p3);
    }
  }
#pragma unroll
  for (int ct = 0; ct < 4; ++ct) {
    float s = lq[ct];
    s += __shfl_xor(s, 16);
    s += __shfl_xor(s, 32);
    if (lane < 16) atomicAdd(&l[b * 2048 + q0 + wc * 64 + ct * 16 + lane], s);
  }
}

// ---------------------------------------------------------------------------
// K4: output GEMM (unchanged r7 structure). outT[d][q] = sum_k ut[d][k] probs[q][k].
__global__ __launch_bounds__(256, 2) void k_out(
    const u16* __restrict__ ut, const u16* __restrict__ probs,
    const float* __restrict__ l, float* __restrict__ out) {
  __shared__ u16 lu[2][8192], lq[2][8192];
  const int blk = blockIdx.x;
  const int xcd = blk & 7, half = xcd & 1, b = xcd >> 1;
  const int idx = blk >> 3;
  const int dtb = half * 2 + (idx >> 4);
  const int qtb = idx & 15;
  const int d0 = dtb * 128, q0 = qtb * 128;
  const int t = threadIdx.x, lane = t & 63, w = t >> 6;
  const int wr = w >> 1, wc = w & 1, ql = lane & 15, g = lane >> 4;
  const f4 fzero = {0.f, 0.f, 0.f, 0.f};
  f4 acc[4][4];
#pragma unroll
  for (int i = 0; i < 4; ++i)
#pragma unroll
    for (int j = 0; j < 4; ++j) acc[i][j] = fzero;

  const u16* ub = &ut[((size_t)b * 512 + d0) * 2048];
  const u16* qb = &probs[((size_t)b * 2048 + q0) * 2048];
  stage_tile(ub, 2048, lu[0], t);
  stage_tile(qb, 2048, lq[0], t);
  PIPE_BARRIER();
  for (int ks = 0; ks < 32; ++ks) {
    const int buf = ks & 1;
    if (ks < 31) {
      stage_tile(ub + (ks + 1) * 64, 2048, lu[buf ^ 1], t);
      stage_tile(qb + (ks + 1) * 64, 2048, lq[buf ^ 1], t);
    }
#pragma unroll
    for (int kk = 0; kk < 2; ++kk) {
      b16x8 ah[4], bh[4];
#pragma unroll
      for (int rt = 0; rt < 4; ++rt)
        ah[rt] = readfrag(lu[buf], wr * 64 + rt * 16 + ql, kk, g);
#pragma unroll
      for (int ct = 0; ct < 4; ++ct)
        bh[ct] = readfrag(lq[buf], wc * 64 + ct * 16 + ql, kk, g);
      __builtin_amdgcn_s_setprio(1);
#pragma unroll
      for (int rt = 0; rt < 4; ++rt)
#pragma unroll
        for (int ct = 0; ct < 4; ++ct)
          acc[rt][ct] = mfma_(ah[rt], bh[ct], acc[rt][ct]);
      __builtin_amdgcn_s_setprio(0);
    }
    PIPE_BARRIER();
  }

#pragma unroll
  for (int ct = 0; ct < 4; ++ct) {
    int q = q0 + wc * 64 + ct * 16 + ql;
    float inv = 1.0f / l[b * 2048 + q];
    size_t orow = ((size_t)b * 2048 + q) * 512;
#pragma unroll
    for (int rt = 0; rt < 4; ++rt) {
      int d = d0 + wr * 64 + rt * 16 + g * 4;
      f4 v = acc[rt][ct] * inv;
      *(f4*)&out[orow + d] = v;
    }
  }
}

// ---------------------------------------------------------------------------
extern "C" void kernel_launch(void* const* d_in, const int* in_sizes, int n_in,
                              void* d_out, int out_size, void* d_ws, size_t ws_size,
                              hipStream_t stream) {
  const float* x = (const float*)d_in[0];
  const float* Wk = (const float*)d_in[1];
  const float* Wq = (const float*)d_in[2];
  const float* Wv = (const float*)d_in[3];
  const float* Wa = (const float*)d_in[4];
  const float* Wb = (const float*)d_in[5];
  float* out = (float*)d_out;

  char* ws = (char*)d_ws;
  size_t off = 0;
  auto alloc = [&](size_t bytes) -> void* {
    void* p = ws + off;
    off += (bytes + 255) & ~(size_t)255;
    return p;
  };
  u16* wh = (u16*)alloc((size_t)1536 * 1024 * 2);
  u16* xh = (u16*)alloc((size_t)8192 * 1024 * 2);
  u16* kh = (u16*)alloc((size_t)8192 * 512 * 2);
  u16* ph = (u16*)alloc((size_t)8192 * 512 * 2);
  u16* ut = (u16*)alloc((size_t)8192 * 512 * 2);
  u16* probs = (u16*)alloc((size_t)4 * 2048 * 2048 * 2);
  float* l = (float*)alloc(8192 * 4);
  u16* waT_h = (u16*)alloc((size_t)512 * 512 * 2);
  u16* waT_l = (u16*)alloc((size_t)512 * 512 * 2);
  u16* wqT_h = (u16*)alloc((size_t)1024 * 512 * 2);
  u16* wqT_l = (u16*)alloc((size_t)1024 * 512 * 2);
  u16* wb_h = (u16*)alloc((size_t)512 * 512 * 2);
  u16* wb_l = (u16*)alloc((size_t)512 * 512 * 2);
  u16* wvT_h = (u16*)alloc((size_t)1024 * 512 * 2);
  u16* wvT_l = (u16*)alloc((size_t)1024 * 512 * 2);
  (void)ws_size; (void)in_sizes; (void)n_in; (void)out_size;

  hipLaunchKernelGGL(k_prep, dim3(9288), dim3(256), 0, stream,
                     x, Wk, Wq, Wv, Wa, Wb, xh, wh,
                     waT_h, waT_l, wqT_h, wqT_l, wb_h, wb_l, wvT_h, wvT_l, l);
  hipLaunchKernelGGL(k_fold_mfma, dim3(64), dim3(256), 0, stream,
                     waT_h, waT_l, wqT_h, wqT_l, wb_h, wb_l, wvT_h, wvT_l, wh);
  hipLaunchKernelGGL(k_proj, dim3(192), dim3(512), 0, stream, xh, wh, kh, ph, ut);
  hipLaunchKernelGGL(k_score, dim3(256), dim3(512), 0, stream, ph, kh, probs, l);
  hipLaunchKernelGGL(k_out, dim3(256), dim3(256), 0, stream, ut, probs, l, out);
}